// Round 1
// baseline (4746.537 us; speedup 1.0000x reference)
//
#include <hip/hip_runtime.h>

// EMA VQ quantizer, fp32-exact baseline.
// Shapes: z[8,4096,512] fp32, codebook[8192,512], ema_count[8192], ema_sum[8192,512]
// Out (float32, concat): z_q_st[16777216], indices[32768], loss_commit[1],
//   loss_embed[1], usage[8192], new_codebook[4194304], new_ema_count[8192],
//   new_ema_sum[4194304]  -> total 25214978

#define DIMC 512
#define NTOK 32768
#define KCB  8192

#define OFF_IDX   16777216UL
#define OFF_LC    16809984UL
#define OFF_LE    16809985UL
#define OFF_USAGE 16809986UL
#define OFF_NCB   16818178UL
#define OFF_NEC   21012482UL
#define OFF_NES   21020674UL

// ws layout (bytes):
//   0      : cand_val float [NTOK*2]
//   262144 : cand_idx int   [NTOK*2]
//   524288 : z2 float [NTOK]
//   655360 : c2 float [KCB]
//   688128 : loss accumulator (double)
// total ~688136 B

// ---------------- norms: z2[row]=sum z^2, c2[k]=sum c^2 ----------------
__global__ __launch_bounds__(256)
void norms_kernel(const float* __restrict__ z, const float* __restrict__ cb,
                  float* __restrict__ z2, float* __restrict__ c2) {
  const int wave = threadIdx.x >> 6, lane = threadIdx.x & 63;
  const int row = blockIdx.x * 4 + wave;          // 0..40959
  const float* src;
  float* dst;
  if (row < NTOK) { src = z + (size_t)row * DIMC;            dst = &z2[row]; }
  else            { src = cb + (size_t)(row - NTOK) * DIMC;  dst = &c2[row - NTOK]; }
  float s = 0.f;
#pragma unroll
  for (int j = 0; j < 2; ++j) {
    float4 v = *(const float4*)&src[(j * 64 + lane) * 4];
    s += v.x * v.x + v.y * v.y + v.z * v.z + v.w * v.w;
  }
#pragma unroll
  for (int off = 32; off; off >>= 1) s += __shfl_down(s, off);
  if (lane == 0) *dst = s;
}

// ---------------- zero scratch accumulators ----------------
__global__ __launch_bounds__(256)
void zero_kernel(float* __restrict__ usage_counts, float* __restrict__ sums,
                 double* __restrict__ loss) {
  const int gid = blockIdx.x * 256 + threadIdx.x;   // 1048576 threads
  float2 zz; zz.x = 0.f; zz.y = 0.f;
  ((float2*)sums)[gid] = zz;
  ((float2*)sums)[gid + 1048576] = zz;
  if (gid < KCB) usage_counts[gid] = 0.f;
  if (gid == 0) *loss = 0.0;
}

// ---------------- fused GEMM + argmin ----------------
#define BM 128
#define BN 128
#define BKD 32
#define LDZ (BM + 4)   // +4 pad: staging-write bank conflict 8-way -> 4-way

__global__ __launch_bounds__(256, 2)
void argmin_kernel(const float* __restrict__ z, const float* __restrict__ cb,
                   const float* __restrict__ z2, const float* __restrict__ c2,
                   float* __restrict__ cand_val, int* __restrict__ cand_idx) {
  __shared__ float zs[BKD][LDZ];
  __shared__ float cs[BKD][LDZ];
  const int tid = threadIdx.x;
  const int tx = tid & 15;      // col group (16 x 8 = 128 cols)
  const int ty = tid >> 4;      // row group (16 x 8 = 128 rows)
  const int m0 = blockIdx.x * BM;
  const int ks = blockIdx.y;                 // K-split: 0 or 1
  const int kt0 = ks * (KCB / BN / 2);       // 32 K-tiles per split

  float bestv[8];
  int   besti[8];
#pragma unroll
  for (int r = 0; r < 8; ++r) { bestv[r] = 3.4e38f; besti[r] = 0x7fffffff; }

  float z2r[8];
#pragma unroll
  for (int r = 0; r < 8; ++r) z2r[r] = z2[m0 + ty * 8 + r];

  for (int kt = kt0; kt < kt0 + KCB / BN / 2; ++kt) {
    const int n0 = kt * BN;
    float acc[8][8];
#pragma unroll
    for (int r = 0; r < 8; ++r)
#pragma unroll
      for (int j = 0; j < 8; ++j) acc[r][j] = 0.f;

    for (int dt = 0; dt < DIMC / BKD; ++dt) {
      const int d0 = dt * BKD;
      __syncthreads();
#pragma unroll
      for (int i = 0; i < 4; ++i) {
        int li = tid + i * 256;             // 0..1023
        int r = li >> 3, c = li & 7;        // 8 float4 per 32-wide row chunk
        float4 v = *(const float4*)&z[(size_t)(m0 + r) * DIMC + d0 + c * 4];
        zs[c * 4 + 0][r] = v.x; zs[c * 4 + 1][r] = v.y;
        zs[c * 4 + 2][r] = v.z; zs[c * 4 + 3][r] = v.w;
      }
#pragma unroll
      for (int i = 0; i < 4; ++i) {
        int li = tid + i * 256;
        int r = li >> 3, c = li & 7;
        float4 v = *(const float4*)&cb[(size_t)(n0 + r) * DIMC + d0 + c * 4];
        cs[c * 4 + 0][r] = v.x; cs[c * 4 + 1][r] = v.y;
        cs[c * 4 + 2][r] = v.z; cs[c * 4 + 3][r] = v.w;
      }
      __syncthreads();
#pragma unroll 8
      for (int kk = 0; kk < BKD; ++kk) {
        float a[8], b[8];
        *(float4*)&a[0] = *(const float4*)&zs[kk][ty * 8];
        *(float4*)&a[4] = *(const float4*)&zs[kk][ty * 8 + 4];
        *(float4*)&b[0] = *(const float4*)&cs[kk][tx * 8];
        *(float4*)&b[4] = *(const float4*)&cs[kk][tx * 8 + 4];
#pragma unroll
        for (int r = 0; r < 8; ++r)
#pragma unroll
          for (int j = 0; j < 8; ++j)
            acc[r][j] = fmaf(a[r], b[j], acc[r][j]);
      }
    }
    // fold this K-tile into the running argmin.
    // dist mimics reference rounding: t = round(z2 + c2); d = round(t - 2*s)
#pragma unroll
    for (int j = 0; j < 8; ++j) {
      const int col = n0 + tx * 8 + j;
      const float cc = c2[col];
#pragma unroll
      for (int r = 0; r < 8; ++r) {
        float t = z2r[r] + cc;
        float d = fmaf(-2.f, acc[r][j], t);   // t - 2*s, single rounding
        if (d < bestv[r]) { bestv[r] = d; besti[r] = col; }  // strict <: first idx wins
      }
    }
  }

  // reduce across the 16 tx groups (LDS reuse)
  __syncthreads();
  float* rv = &zs[0][0];
  int*   ri = (int*)&cs[0][0];
#pragma unroll
  for (int r = 0; r < 8; ++r) {
    rv[(ty * 8 + r) * 16 + tx] = bestv[r];
    ri[(ty * 8 + r) * 16 + tx] = besti[r];
  }
  __syncthreads();
  if (tid < BM) {
    float bv = rv[tid * 16];
    int   bi = ri[tid * 16];
#pragma unroll
    for (int t = 1; t < 16; ++t) {
      float v = rv[tid * 16 + t]; int ii = ri[tid * 16 + t];
      if (v < bv || (v == bv && ii < bi)) { bv = v; bi = ii; }
    }
    cand_val[(size_t)(m0 + tid) * 2 + ks] = bv;
    cand_idx[(size_t)(m0 + tid) * 2 + ks] = bi;
  }
}

// ---------------- gather z_q, scatter sums/counts, loss ----------------
__global__ __launch_bounds__(128)
void gather_kernel(const float* __restrict__ z, const float* __restrict__ cb,
                   const float* __restrict__ cand_val, const int* __restrict__ cand_idx,
                   float* __restrict__ out, float* __restrict__ counts_acc,
                   float* __restrict__ sums_acc, double* __restrict__ loss_acc) {
  const int token = blockIdx.x;
  const int tid = threadIdx.x;    // 128 threads, 1 float4 each
  const float v0 = cand_val[token * 2 + 0], v1 = cand_val[token * 2 + 1];
  const int   i0 = cand_idx[token * 2 + 0], i1 = cand_idx[token * 2 + 1];
  const int idx = (v1 < v0 || (v1 == v0 && i1 < i0)) ? i1 : i0;
  if (tid == 0) {
    out[OFF_IDX + token] = (float)idx;
    unsafeAtomicAdd(&counts_acc[idx], 1.0f);
  }
  const float4 zv = *(const float4*)&z[(size_t)token * DIMC + tid * 4];
  const float4 cv = *(const float4*)&cb[(size_t)idx * DIMC + tid * 4];
  float4 o;
  o.x = zv.x + (cv.x - zv.x);   // exact reference expression z + (z_q - z)
  o.y = zv.y + (cv.y - zv.y);
  o.z = zv.z + (cv.z - zv.z);
  o.w = zv.w + (cv.w - zv.w);
  *(float4*)&out[(size_t)token * DIMC + tid * 4] = o;
  const float ex = cv.x - zv.x, ey = cv.y - zv.y, ez = cv.z - zv.z, ew = cv.w - zv.w;
  float lsum = ex * ex; lsum += ey * ey; lsum += ez * ez; lsum += ew * ew;
  float* sp = &sums_acc[(size_t)idx * DIMC + tid * 4];
  unsafeAtomicAdd(sp + 0, zv.x);
  unsafeAtomicAdd(sp + 1, zv.y);
  unsafeAtomicAdd(sp + 2, zv.z);
  unsafeAtomicAdd(sp + 3, zv.w);
#pragma unroll
  for (int off = 32; off; off >>= 1) lsum += __shfl_down(lsum, off);
  if ((tid & 63) == 0) unsafeAtomicAdd(loss_acc, (double)lsum);
}

// ---------------- finalize EMA matrices (float2: slots are only 8B-aligned) ---
__global__ __launch_bounds__(256)
void finalize_mat(const float* __restrict__ ema_sum_in, const float* __restrict__ ema_cnt_in,
                  const float* __restrict__ counts_raw, float* __restrict__ nes,
                  float* __restrict__ ncb) {
  const int i2 = blockIdx.x * 256 + threadIdx.x;   // 0..2097151
  const size_t base = (size_t)i2 * 2;
  const int k = i2 >> 8;                            // 256 float2 per row
  const float c = counts_raw[k];
  const float ncnt = ema_cnt_in[k] * 0.99f + c * 0.01f;
  const float denom = fmaxf(ncnt, 1.0f);
  float2 s = *(float2*)&nes[base];                  // raw segment sums
  float2 e = *(const float2*)&ema_sum_in[base];
  float2 ns; ns.x = e.x * 0.99f + s.x * 0.01f; ns.y = e.y * 0.99f + s.y * 0.01f;
  *(float2*)&nes[base] = ns;
  float2 q; q.x = ns.x / denom; q.y = ns.y / denom;
  *(float2*)&ncb[base] = q;
}

// ---------------- finalize usage / new_ema_count / losses ----------------
__global__ __launch_bounds__(256)
void finalize_small(const float* __restrict__ ema_cnt_in, float* __restrict__ usage_io,
                    float* __restrict__ new_cnt_out, const double* __restrict__ loss_acc,
                    float* __restrict__ loss_out) {
  const int k = blockIdx.x * 256 + threadIdx.x;   // 8192 exact
  const float c = usage_io[k];
  usage_io[k] = c / 32768.0f;                      // total == N always (exact)
  new_cnt_out[k] = ema_cnt_in[k] * 0.99f + c * 0.01f;
  if (k == 0) {
    const float l = (float)(*loss_acc / 16777216.0);
    loss_out[0] = l;   // loss_commit
    loss_out[1] = l;   // loss_embed (identical forward value)
  }
}

extern "C" void kernel_launch(void* const* d_in, const int* in_sizes, int n_in,
                              void* d_out, int out_size, void* d_ws, size_t ws_size,
                              hipStream_t stream) {
  const float* z       = (const float*)d_in[0];
  const float* cb      = (const float*)d_in[1];
  const float* ema_cnt = (const float*)d_in[2];
  const float* ema_sum = (const float*)d_in[3];
  float* out = (float*)d_out;
  char* ws = (char*)d_ws;
  float*  cand_val = (float*)(ws);
  int*    cand_idx = (int*)(ws + 262144);
  float*  z2       = (float*)(ws + 524288);
  float*  c2       = (float*)(ws + 655360);
  double* loss     = (double*)(ws + 688128);

  norms_kernel<<<(NTOK + KCB) / 4, 256, 0, stream>>>(z, cb, z2, c2);
  zero_kernel<<<4096, 256, 0, stream>>>(out + OFF_USAGE, out + OFF_NES, loss);
  argmin_kernel<<<dim3(NTOK / BM, 2), 256, 0, stream>>>(z, cb, z2, c2, cand_val, cand_idx);
  gather_kernel<<<NTOK, 128, 0, stream>>>(z, cb, cand_val, cand_idx, out,
                                          out + OFF_USAGE, out + OFF_NES, loss);
  finalize_mat<<<8192, 256, 0, stream>>>(ema_sum, ema_cnt, out + OFF_USAGE,
                                         out + OFF_NES, out + OFF_NCB);
  finalize_small<<<32, 256, 0, stream>>>(ema_cnt, out + OFF_USAGE, out + OFF_NEC,
                                         loss, out + OFF_LC);
}

// Round 2
// 2000.234 us; speedup vs baseline: 2.3730x; 2.3730x over previous
//
#include <hip/hip_runtime.h>

// EMA VQ quantizer. Distance GEMM on bf16 matrix cores via bf16x3 split
// (zh*ch + zh*cl + zl*ch), fp32 epilogue replicating reference rounding.
// Shapes: z[8,4096,512] fp32, codebook[8192,512], ema_count[8192], ema_sum[8192,512]
// Out (float32, concat): z_q_st[16777216], indices[32768], loss_commit[1],
//   loss_embed[1], usage[8192], new_codebook[4194304], new_ema_count[8192],
//   new_ema_sum[4194304]

#define DIMC 512
#define NTOK 32768
#define KCB  8192

#define OFF_IDX   16777216UL
#define OFF_LC    16809984UL
#define OFF_LE    16809985UL
#define OFF_USAGE 16809986UL
#define OFF_NCB   16818178UL
#define OFF_NEC   21012482UL
#define OFF_NES   21020674UL

typedef unsigned short u16;
typedef unsigned int u32;
typedef __attribute__((ext_vector_type(8))) short short8;
typedef __attribute__((ext_vector_type(8))) u16 ushort8;
typedef __attribute__((ext_vector_type(4))) float f32x4;

__device__ __forceinline__ u16 f2bf(float x) {          // RNE float->bf16
  u32 u = __float_as_uint(x);
  return (u16)((u + 0x7fffu + ((u >> 16) & 1u)) >> 16);
}
__device__ __forceinline__ float bf2f(u16 h) { return __uint_as_float(((u32)h) << 16); }

#define GLL16(g, l) __builtin_amdgcn_global_load_lds( \
    (const __attribute__((address_space(1))) u32*)(g), \
    (__attribute__((address_space(3))) u32*)(l), 16, 0, 0)

// ---- fused convert (fp32 -> zh/zl bf16, swizzled-tiled) + row sum-of-squares ----
// Tiled layout: [tile][kstep 0..15][row 0..127][granule 0..3] of 8 bf16, with
// granule position s ^= (row>>1)&3  (bank-conflict-free ds_read_b128 later).
__global__ __launch_bounds__(256)
void conv_norms(const float* __restrict__ z, const float* __restrict__ cb,
                u16* __restrict__ zh, u16* __restrict__ zl,
                u16* __restrict__ ch, u16* __restrict__ cl,
                float* __restrict__ z2, float* __restrict__ c2) {
  const int gid = blockIdx.x * 256 + threadIdx.x;   // wave = one row (64 granules)
  const int lane = threadIdx.x & 63;
  int t = gid >> 6;
  const int g = gid & 63;
  const float* src; u16 *dh, *dl; float* nrm;
  if (t < NTOK) { src = z; dh = zh; dl = zl; nrm = z2; }
  else { t -= NTOK; src = cb; dh = ch; dl = cl; nrm = c2; }
  const float* p = src + (size_t)t * DIMC + g * 8;
  float4 v0 = *(const float4*)p;
  float4 v1 = *(const float4*)(p + 4);
  float in[8] = {v0.x, v0.y, v0.z, v0.w, v1.x, v1.y, v1.z, v1.w};
  ushort8 h, l;
  float ss = 0.f;
#pragma unroll
  for (int j = 0; j < 8; ++j) {
    ss += in[j] * in[j];
    u16 hb = f2bf(in[j]);
    h[j] = hb;
    l[j] = f2bf(in[j] - bf2f(hb));   // exact residual (Sterbenz)
  }
  const int mt = t >> 7, r = t & 127, ks = g >> 2, s = g & 3;
  const int sp = s ^ ((r >> 1) & 3);
  const size_t base = ((((size_t)mt * 16 + ks) * 128 + r) * 4 + sp) * 8;
  *(ushort8*)&dh[base] = h;
  *(ushort8*)&dl[base] = l;
#pragma unroll
  for (int off = 32; off; off >>= 1) ss += __shfl_down(ss, off);
  if (lane == 0) nrm[t] = ss;
}

// ---- init packed argmin keys + loss ----
__global__ __launch_bounds__(256)
void initkeys(unsigned long long* __restrict__ keys, double* __restrict__ loss) {
  const int i = blockIdx.x * 256 + threadIdx.x;   // 32768
  keys[i] = 0xFFFFFFFFFFFFFFFFull;
  if (i == 0) *loss = 0.0;
}

// ---- bf16x3 MFMA GEMM + fused argmin (packed u64 atomicMin) ----
__global__ __launch_bounds__(256)
void argmin_kernel(const u16* __restrict__ zh, const u16* __restrict__ zl,
                   const u16* __restrict__ ch, const u16* __restrict__ cl,
                   const float* __restrict__ z2, const float* __restrict__ c2,
                   unsigned long long* __restrict__ keys) {
  __shared__ __align__(16) char lds[32768];       // zh|zl|ch|cl tiles, 8KB each
  const int tid = threadIdx.x;
  const int mt = blockIdx.x, nt = blockIdx.y;
  const int lane = tid & 63;
  const int wid = tid >> 6;
  const int wr = wid >> 1, wn = wid & 1;          // 2x2 wave grid, 64x64 each
  const int lg = lane >> 4, lr = lane & 15;

  f32x4 acc[4][4];
#pragma unroll
  for (int m = 0; m < 4; ++m)
#pragma unroll
    for (int n = 0; n < 4; ++n) acc[m][n] = (f32x4)(0.f);

  const size_t abase = (size_t)mt * (16 * 4096);  // elements per tile-row of ksteps
  const size_t bbase = (size_t)nt * (16 * 4096);
  char* const la  = lds;
  char* const lal = lds + 8192;
  char* const lb  = lds + 16384;
  char* const lbl = lds + 24576;
  const int wlds = wid * 1024;                    // wave's linear 1KB LDS slice
  const int goff = tid * 8;                       // element offset into 4KB half

  int aoff[4], boff[4];                           // swizzled frag byte offsets
#pragma unroll
  for (int m = 0; m < 4; ++m) {
    const int r = wr * 64 + m * 16 + lr;
    aoff[m] = r * 64 + ((lg ^ ((r >> 1) & 3)) * 16);
  }
#pragma unroll
  for (int n = 0; n < 4; ++n) {
    const int c = wn * 64 + n * 16 + lr;
    boff[n] = c * 64 + ((lg ^ ((c >> 1) & 3)) * 16);
  }

  for (int ks = 0; ks < 16; ++ks) {
    const size_t ao = abase + ks * 4096;
    const size_t bo = bbase + ks * 4096;
    __syncthreads();                              // prev-step frag reads done
    GLL16(zh + ao + goff,        la  + wlds);
    GLL16(zh + ao + 2048 + goff, la  + 4096 + wlds);
    GLL16(zl + ao + goff,        lal + wlds);
    GLL16(zl + ao + 2048 + goff, lal + 4096 + wlds);
    GLL16(ch + bo + goff,        lb  + wlds);
    GLL16(ch + bo + 2048 + goff, lb  + 4096 + wlds);
    GLL16(cl + bo + goff,        lbl + wlds);
    GLL16(cl + bo + 2048 + goff, lbl + 4096 + wlds);
    __syncthreads();                              // vmcnt(0) drain: tiles ready
    short8 ah[4], alo[4], bh[4], blo[4];
#pragma unroll
    for (int m = 0; m < 4; ++m) {
      ah[m]  = *(const short8*)(la  + aoff[m]);
      alo[m] = *(const short8*)(lal + aoff[m]);
    }
#pragma unroll
    for (int n = 0; n < 4; ++n) {
      bh[n]  = *(const short8*)(lb  + boff[n]);
      blo[n] = *(const short8*)(lbl + boff[n]);
    }
#pragma unroll
    for (int m = 0; m < 4; ++m)
#pragma unroll
      for (int n = 0; n < 4; ++n) {
        acc[m][n] = __builtin_amdgcn_mfma_f32_16x16x32_bf16(alo[m], bh[n],  acc[m][n], 0, 0, 0);
        acc[m][n] = __builtin_amdgcn_mfma_f32_16x16x32_bf16(ah[m],  blo[n], acc[m][n], 0, 0, 0);
        acc[m][n] = __builtin_amdgcn_mfma_f32_16x16x32_bf16(ah[m],  bh[n],  acc[m][n], 0, 0, 0);
      }
  }

  // epilogue: dist = fmaf(-2, dot, z2+c2) — same rounding as reference.
  // C/D layout: col = lane&15, row = (lane>>4)*4 + reg  [m89/m91 verified]
  const int row0 = mt * 128 + wr * 64;
  const int col0 = nt * 128 + wn * 64;
  float z2r[4][4];
#pragma unroll
  for (int m = 0; m < 4; ++m)
#pragma unroll
    for (int q = 0; q < 4; ++q)
      z2r[m][q] = z2[row0 + m * 16 + lg * 4 + q];
  float bv[4][4]; int bi[4][4];
#pragma unroll
  for (int m = 0; m < 4; ++m)
#pragma unroll
    for (int q = 0; q < 4; ++q) { bv[m][q] = 3.4e38f; bi[m][q] = 0x7fffffff; }
#pragma unroll
  for (int n = 0; n < 4; ++n) {
    const int cc = col0 + n * 16 + lr;
    const float c2v = c2[cc];
#pragma unroll
    for (int m = 0; m < 4; ++m)
#pragma unroll
      for (int q = 0; q < 4; ++q) {
        const float d = fmaf(-2.f, acc[m][n][q], z2r[m][q] + c2v);
        if (d < bv[m][q]) { bv[m][q] = d; bi[m][q] = cc; }  // n ascending => first idx wins
      }
  }
#pragma unroll
  for (int off = 1; off < 16; off <<= 1) {        // reduce across the 16 col-lanes
#pragma unroll
    for (int m = 0; m < 4; ++m)
#pragma unroll
      for (int q = 0; q < 4; ++q) {
        const float ov = __shfl_xor(bv[m][q], off);
        const int oi = __shfl_xor(bi[m][q], off);
        if (ov < bv[m][q] || (ov == bv[m][q] && oi < bi[m][q])) { bv[m][q] = ov; bi[m][q] = oi; }
      }
  }
  if (lr == 0) {
#pragma unroll
    for (int m = 0; m < 4; ++m)
#pragma unroll
      for (int q = 0; q < 4; ++q) {
        const int token = row0 + m * 16 + lg * 4 + q;
        const unsigned long long pk =
            ((unsigned long long)__float_as_uint(bv[m][q]) << 32) | (u32)bi[m][q];
        atomicMin(&keys[token], pk);              // dist>0 => float bits monotone
      }
  }
}

// ---- zero scratch accumulators (usage counts + raw segment sums) ----
__global__ __launch_bounds__(256)
void zero_kernel(float* __restrict__ usage_counts, float* __restrict__ sums) {
  const int gid = blockIdx.x * 256 + threadIdx.x;   // 1048576 threads
  float2 zz; zz.x = 0.f; zz.y = 0.f;
  ((float2*)sums)[gid] = zz;
  ((float2*)sums)[gid + 1048576] = zz;
  if (gid < KCB) usage_counts[gid] = 0.f;
}

// ---- gather z_q, scatter sums/counts, loss ----
__global__ __launch_bounds__(128)
void gather_kernel(const float* __restrict__ z, const float* __restrict__ cb,
                   const unsigned long long* __restrict__ keys,
                   float* __restrict__ out, float* __restrict__ counts_acc,
                   float* __restrict__ sums_acc, double* __restrict__ loss_acc) {
  const int token = blockIdx.x;
  const int tid = threadIdx.x;    // 128 threads, 1 float4 each
  const int idx = (int)(u32)(keys[token] & 0xFFFFFFFFull);
  if (tid == 0) {
    out[OFF_IDX + token] = (float)idx;
    unsafeAtomicAdd(&counts_acc[idx], 1.0f);
  }
  const float4 zv = *(const float4*)&z[(size_t)token * DIMC + tid * 4];
  const float4 cv = *(const float4*)&cb[(size_t)idx * DIMC + tid * 4];
  float4 o;
  o.x = zv.x + (cv.x - zv.x);   // exact reference expression z + (z_q - z)
  o.y = zv.y + (cv.y - zv.y);
  o.z = zv.z + (cv.z - zv.z);
  o.w = zv.w + (cv.w - zv.w);
  *(float4*)&out[(size_t)token * DIMC + tid * 4] = o;
  const float ex = cv.x - zv.x, ey = cv.y - zv.y, ez = cv.z - zv.z, ew = cv.w - zv.w;
  float lsum = ex * ex; lsum += ey * ey; lsum += ez * ez; lsum += ew * ew;
  float* sp = &sums_acc[(size_t)idx * DIMC + tid * 4];
  unsafeAtomicAdd(sp + 0, zv.x);
  unsafeAtomicAdd(sp + 1, zv.y);
  unsafeAtomicAdd(sp + 2, zv.z);
  unsafeAtomicAdd(sp + 3, zv.w);
#pragma unroll
  for (int off = 32; off; off >>= 1) lsum += __shfl_down(lsum, off);
  if ((tid & 63) == 0) unsafeAtomicAdd(loss_acc, (double)lsum);
}

// ---- finalize EMA matrices (float2: slots are only 8B-aligned) ----
__global__ __launch_bounds__(256)
void finalize_mat(const float* __restrict__ ema_sum_in, const float* __restrict__ ema_cnt_in,
                  const float* __restrict__ counts_raw, float* __restrict__ nes,
                  float* __restrict__ ncb) {
  const int i2 = blockIdx.x * 256 + threadIdx.x;   // 0..2097151
  const size_t base = (size_t)i2 * 2;
  const int k = i2 >> 8;                            // 256 float2 per row
  const float c = counts_raw[k];
  const float ncnt = ema_cnt_in[k] * 0.99f + c * 0.01f;
  const float denom = fmaxf(ncnt, 1.0f);
  float2 s = *(float2*)&nes[base];                  // raw segment sums
  float2 e = *(const float2*)&ema_sum_in[base];
  float2 ns; ns.x = e.x * 0.99f + s.x * 0.01f; ns.y = e.y * 0.99f + s.y * 0.01f;
  *(float2*)&nes[base] = ns;
  float2 q; q.x = ns.x / denom; q.y = ns.y / denom;
  *(float2*)&ncb[base] = q;
}

// ---- finalize usage / new_ema_count / losses ----
__global__ __launch_bounds__(256)
void finalize_small(const float* __restrict__ ema_cnt_in, float* __restrict__ usage_io,
                    float* __restrict__ new_cnt_out, const double* __restrict__ loss_acc,
                    float* __restrict__ loss_out) {
  const int k = blockIdx.x * 256 + threadIdx.x;   // 8192 exact
  const float c = usage_io[k];
  usage_io[k] = c / 32768.0f;                      // total == N always
  new_cnt_out[k] = ema_cnt_in[k] * 0.99f + c * 0.01f;
  if (k == 0) {
    const float l = (float)(*loss_acc / 16777216.0);
    loss_out[0] = l;   // loss_commit
    loss_out[1] = l;   // loss_embed (identical forward value)
  }
}

extern "C" void kernel_launch(void* const* d_in, const int* in_sizes, int n_in,
                              void* d_out, int out_size, void* d_ws, size_t ws_size,
                              hipStream_t stream) {
  const float* z       = (const float*)d_in[0];
  const float* cb      = (const float*)d_in[1];
  const float* ema_cnt = (const float*)d_in[2];
  const float* ema_sum = (const float*)d_in[3];
  float* out = (float*)d_out;
  char* ws = (char*)d_ws;

  // bf16 operand scratch lives in not-yet-written output regions:
  //   zh/zl -> z_q slot (64MB exactly); ch -> NCB slot (+2 floats for 16B align);
  //   cl -> NES slot (+2). All overwritten by real outputs later in the stream.
  u16* zh = (u16*)out;
  u16* zl = (u16*)(out + 8388608);
  u16* ch = (u16*)(out + OFF_NCB + 2);
  u16* cl = (u16*)(out + OFF_NES + 2);
  unsigned long long* keys = (unsigned long long*)ws;   // [32768] packed (dist,idx)
  float*  z2   = (float*)(ws + 262144);
  float*  c2   = (float*)(ws + 393216);
  double* loss = (double*)(ws + 425984);

  conv_norms<<<10240, 256, 0, stream>>>(z, cb, zh, zl, ch, cl, z2, c2);
  initkeys<<<128, 256, 0, stream>>>(keys, loss);
  argmin_kernel<<<dim3(256, 64), 256, 0, stream>>>(zh, zl, ch, cl, z2, c2, keys);
  zero_kernel<<<4096, 256, 0, stream>>>(out + OFF_USAGE, out + OFF_NES);
  gather_kernel<<<NTOK, 128, 0, stream>>>(z, cb, keys, out,
                                          out + OFF_USAGE, out + OFF_NES, loss);
  finalize_mat<<<8192, 256, 0, stream>>>(ema_sum, ema_cnt, out + OFF_USAGE,
                                         out + OFF_NES, out + OFF_NCB);
  finalize_small<<<32, 256, 0, stream>>>(ema_cnt, out + OFF_USAGE, out + OFF_NEC,
                                         loss, out + OFF_LC);
}

// Round 3
// 1971.178 us; speedup vs baseline: 2.4080x; 1.0147x over previous
//
#include <hip/hip_runtime.h>

// EMA VQ quantizer. Distance GEMM on bf16 matrix cores via bf16x3 split
// (zh*ch + zh*cl + zl*ch), fp32 epilogue replicating reference rounding.
// Segment sums via counting-sort + per-code gather (no f32 atomics).
// Shapes: z[8,4096,512] fp32, codebook[8192,512], ema_count[8192], ema_sum[8192,512]
// Out (float32, concat): z_q_st[16777216], indices[32768], loss_commit[1],
//   loss_embed[1], usage[8192], new_codebook[4194304], new_ema_count[8192],
//   new_ema_sum[4194304]

#define DIMC 512
#define NTOK 32768
#define KCB  8192

#define OFF_IDX   16777216UL
#define OFF_LC    16809984UL
#define OFF_LE    16809985UL
#define OFF_USAGE 16809986UL
#define OFF_NCB   16818178UL
#define OFF_NEC   21012482UL
#define OFF_NES   21020674UL

typedef unsigned short u16;
typedef unsigned int u32;
typedef __attribute__((ext_vector_type(8))) short short8;
typedef __attribute__((ext_vector_type(8))) u16 ushort8;
typedef __attribute__((ext_vector_type(4))) float f32x4;

__device__ __forceinline__ u16 f2bf(float x) {          // RNE float->bf16
  u32 u = __float_as_uint(x);
  return (u16)((u + 0x7fffu + ((u >> 16) & 1u)) >> 16);
}
__device__ __forceinline__ float bf2f(u16 h) { return __uint_as_float(((u32)h) << 16); }

#define GLL16(g, l) __builtin_amdgcn_global_load_lds( \
    (const __attribute__((address_space(1))) u32*)(g), \
    (__attribute__((address_space(3))) u32*)(l), 16, 0, 0)

// ---- fused convert (fp32 -> zh/zl bf16, swizzled-tiled) + row sum-of-squares ----
// Tiled layout: [tile][kstep 0..15][row 0..127][granule 0..3] of 8 bf16, with
// granule position s ^= (row>>1)&3  (bank-conflict-free ds_read_b128 later).
__global__ __launch_bounds__(256)
void conv_norms(const float* __restrict__ z, const float* __restrict__ cb,
                u16* __restrict__ zh, u16* __restrict__ zl,
                u16* __restrict__ ch, u16* __restrict__ cl,
                float* __restrict__ z2, float* __restrict__ c2) {
  const int gid = blockIdx.x * 256 + threadIdx.x;   // wave = one row (64 granules)
  const int lane = threadIdx.x & 63;
  int t = gid >> 6;
  const int g = gid & 63;
  const float* src; u16 *dh, *dl; float* nrm;
  if (t < NTOK) { src = z; dh = zh; dl = zl; nrm = z2; }
  else { t -= NTOK; src = cb; dh = ch; dl = cl; nrm = c2; }
  const float* p = src + (size_t)t * DIMC + g * 8;
  float4 v0 = *(const float4*)p;
  float4 v1 = *(const float4*)(p + 4);
  float in[8] = {v0.x, v0.y, v0.z, v0.w, v1.x, v1.y, v1.z, v1.w};
  ushort8 h, l;
  float ss = 0.f;
#pragma unroll
  for (int j = 0; j < 8; ++j) {
    ss += in[j] * in[j];
    u16 hb = f2bf(in[j]);
    h[j] = hb;
    l[j] = f2bf(in[j] - bf2f(hb));   // exact residual (Sterbenz)
  }
  const int mt = t >> 7, r = t & 127, ks = g >> 2, s = g & 3;
  const int sp = s ^ ((r >> 1) & 3);
  const size_t base = ((((size_t)mt * 16 + ks) * 128 + r) * 4 + sp) * 8;
  *(ushort8*)&dh[base] = h;
  *(ushort8*)&dl[base] = l;
#pragma unroll
  for (int off = 32; off; off >>= 1) ss += __shfl_down(ss, off);
  if (lane == 0) nrm[t] = ss;
}

// ---- init packed argmin keys + counts + loss ----
__global__ __launch_bounds__(256)
void init_kernel(unsigned long long* __restrict__ keys, int* __restrict__ counts,
                 double* __restrict__ loss) {
  const int i = blockIdx.x * 256 + threadIdx.x;   // 32768
  keys[i] = 0xFFFFFFFFFFFFFFFFull;
  if (i < KCB) counts[i] = 0;
  if (i == 0) *loss = 0.0;
}

// ---- bf16x3 MFMA GEMM + fused argmin (packed u64 atomicMin) ----
__global__ __launch_bounds__(256)
void argmin_kernel(const u16* __restrict__ zh, const u16* __restrict__ zl,
                   const u16* __restrict__ ch, const u16* __restrict__ cl,
                   const float* __restrict__ z2, const float* __restrict__ c2,
                   unsigned long long* __restrict__ keys) {
  __shared__ __align__(16) char lds[32768];       // zh|zl|ch|cl tiles, 8KB each
  const int tid = threadIdx.x;
  const int mt = blockIdx.x, nt = blockIdx.y;
  const int lane = tid & 63;
  const int wid = tid >> 6;
  const int wr = wid >> 1, wn = wid & 1;          // 2x2 wave grid, 64x64 each
  const int lg = lane >> 4, lr = lane & 15;

  f32x4 acc[4][4];
#pragma unroll
  for (int m = 0; m < 4; ++m)
#pragma unroll
    for (int n = 0; n < 4; ++n) acc[m][n] = (f32x4)(0.f);

  const size_t abase = (size_t)mt * (16 * 4096);  // elements per tile-row of ksteps
  const size_t bbase = (size_t)nt * (16 * 4096);
  char* const la  = lds;
  char* const lal = lds + 8192;
  char* const lb  = lds + 16384;
  char* const lbl = lds + 24576;
  const int wlds = wid * 1024;                    // wave's linear 1KB LDS slice
  const int goff = tid * 8;                       // element offset into 4KB half

  int aoff[4], boff[4];                           // swizzled frag byte offsets
#pragma unroll
  for (int m = 0; m < 4; ++m) {
    const int r = wr * 64 + m * 16 + lr;
    aoff[m] = r * 64 + ((lg ^ ((r >> 1) & 3)) * 16);
  }
#pragma unroll
  for (int n = 0; n < 4; ++n) {
    const int c = wn * 64 + n * 16 + lr;
    boff[n] = c * 64 + ((lg ^ ((c >> 1) & 3)) * 16);
  }

  for (int ks = 0; ks < 16; ++ks) {
    const size_t ao = abase + ks * 4096;
    const size_t bo = bbase + ks * 4096;
    __syncthreads();                              // prev-step frag reads done
    GLL16(zh + ao + goff,        la  + wlds);
    GLL16(zh + ao + 2048 + goff, la  + 4096 + wlds);
    GLL16(zl + ao + goff,        lal + wlds);
    GLL16(zl + ao + 2048 + goff, lal + 4096 + wlds);
    GLL16(ch + bo + goff,        lb  + wlds);
    GLL16(ch + bo + 2048 + goff, lb  + 4096 + wlds);
    GLL16(cl + bo + goff,        lbl + wlds);
    GLL16(cl + bo + 2048 + goff, lbl + 4096 + wlds);
    __syncthreads();                              // vmcnt(0) drain: tiles ready
    short8 ah[4], alo[4], bh[4], blo[4];
#pragma unroll
    for (int m = 0; m < 4; ++m) {
      ah[m]  = *(const short8*)(la  + aoff[m]);
      alo[m] = *(const short8*)(lal + aoff[m]);
    }
#pragma unroll
    for (int n = 0; n < 4; ++n) {
      bh[n]  = *(const short8*)(lb  + boff[n]);
      blo[n] = *(const short8*)(lbl + boff[n]);
    }
#pragma unroll
    for (int m = 0; m < 4; ++m)
#pragma unroll
      for (int n = 0; n < 4; ++n) {
        acc[m][n] = __builtin_amdgcn_mfma_f32_16x16x32_bf16(alo[m], bh[n],  acc[m][n], 0, 0, 0);
        acc[m][n] = __builtin_amdgcn_mfma_f32_16x16x32_bf16(ah[m],  blo[n], acc[m][n], 0, 0, 0);
        acc[m][n] = __builtin_amdgcn_mfma_f32_16x16x32_bf16(ah[m],  bh[n],  acc[m][n], 0, 0, 0);
      }
  }

  // epilogue: dist = fmaf(-2, dot, z2+c2) — same rounding as reference.
  // C/D layout: col = lane&15, row = (lane>>4)*4 + reg  [m89/m91 verified]
  const int row0 = mt * 128 + wr * 64;
  const int col0 = nt * 128 + wn * 64;
  float z2r[4][4];
#pragma unroll
  for (int m = 0; m < 4; ++m)
#pragma unroll
    for (int q = 0; q < 4; ++q)
      z2r[m][q] = z2[row0 + m * 16 + lg * 4 + q];
  float bv[4][4]; int bi[4][4];
#pragma unroll
  for (int m = 0; m < 4; ++m)
#pragma unroll
    for (int q = 0; q < 4; ++q) { bv[m][q] = 3.4e38f; bi[m][q] = 0x7fffffff; }
#pragma unroll
  for (int n = 0; n < 4; ++n) {
    const int cc = col0 + n * 16 + lr;
    const float c2v = c2[cc];
#pragma unroll
    for (int m = 0; m < 4; ++m)
#pragma unroll
      for (int q = 0; q < 4; ++q) {
        const float d = fmaf(-2.f, acc[m][n][q], z2r[m][q] + c2v);
        if (d < bv[m][q]) { bv[m][q] = d; bi[m][q] = cc; }  // n ascending => first idx wins
      }
  }
#pragma unroll
  for (int off = 1; off < 16; off <<= 1) {        // reduce across the 16 col-lanes
#pragma unroll
    for (int m = 0; m < 4; ++m)
#pragma unroll
      for (int q = 0; q < 4; ++q) {
        const float ov = __shfl_xor(bv[m][q], off);
        const int oi = __shfl_xor(bi[m][q], off);
        if (ov < bv[m][q] || (ov == bv[m][q] && oi < bi[m][q])) { bv[m][q] = ov; bi[m][q] = oi; }
      }
  }
  if (lr == 0) {
#pragma unroll
    for (int m = 0; m < 4; ++m)
#pragma unroll
      for (int q = 0; q < 4; ++q) {
        const int token = row0 + m * 16 + lg * 4 + q;
        const unsigned long long pk =
            ((unsigned long long)__float_as_uint(bv[m][q]) << 32) | (u32)bi[m][q];
        atomicMin(&keys[token], pk);              // dist>0 => float bits monotone
      }
  }
}

// ---- histogram + indices output ----
__global__ __launch_bounds__(256)
void hist_kernel(const unsigned long long* __restrict__ keys,
                 int* __restrict__ counts, float* __restrict__ idx_out) {
  const int t = blockIdx.x * 256 + threadIdx.x;   // 32768
  const int idx = (int)(u32)(keys[t] & 0xFFFFFFFFull);
  idx_out[t] = (float)idx;
  atomicAdd(&counts[idx], 1);
}

// ---- one-block exclusive scan of counts; fuse usage + new_ema_count ----
__global__ __launch_bounds__(1024)
void scan_kernel(const int* __restrict__ counts, int* __restrict__ offsets,
                 const float* __restrict__ ema_cnt, float* __restrict__ usage_out,
                 float* __restrict__ nec_out) {
  __shared__ int wsum[16];
  const int t = threadIdx.x;            // 0..1023, 8 bins each
  const int lane = t & 63, w = t >> 6;
  int v[8]; int tot = 0;
#pragma unroll
  for (int j = 0; j < 8; ++j) { v[j] = counts[t * 8 + j]; tot += v[j]; }
  int s = tot;                          // inclusive wave scan of thread totals
#pragma unroll
  for (int off = 1; off < 64; off <<= 1) {
    const int u = __shfl_up(s, off);
    if (lane >= off) s += u;
  }
  if (lane == 63) wsum[w] = s;
  __syncthreads();
  if (t == 0) { int a = 0; for (int i = 0; i < 16; ++i) { int b = wsum[i]; wsum[i] = a; a += b; } }
  __syncthreads();
  int base = wsum[w] + (s - tot);       // exclusive base for this thread's 8 bins
#pragma unroll
  for (int j = 0; j < 8; ++j) {
    const int k = t * 8 + j;
    offsets[k] = base;
    usage_out[k] = (float)v[j] * (1.0f / 32768.0f);   // exact: /2^15
    nec_out[k] = ema_cnt[k] * 0.99f + (float)v[j] * 0.01f;
    base += v[j];
  }
}

// ---- scatter token ids into per-code lists ----
__global__ __launch_bounds__(256)
void scatter_kernel(const unsigned long long* __restrict__ keys,
                    int* __restrict__ offsets, int* __restrict__ list) {
  const int t = blockIdx.x * 256 + threadIdx.x;   // 32768
  const int idx = (int)(u32)(keys[t] & 0xFFFFFFFFull);
  const int pos = atomicAdd(&offsets[idx], 1);    // offsets become segment ends
  list[pos] = t;
}

// ---- z_q_st + loss (no scatter) ----
__global__ __launch_bounds__(128)
void zq_loss_kernel(const float* __restrict__ z, const float* __restrict__ cb,
                    const unsigned long long* __restrict__ keys,
                    float* __restrict__ out, double* __restrict__ loss_acc) {
  const int token = blockIdx.x;
  const int tid = threadIdx.x;    // 128 threads, 1 float4 each
  const int idx = (int)(u32)(keys[token] & 0xFFFFFFFFull);
  const float4 zv = *(const float4*)&z[(size_t)token * DIMC + tid * 4];
  const float4 cv = *(const float4*)&cb[(size_t)idx * DIMC + tid * 4];
  float4 o;
  o.x = zv.x + (cv.x - zv.x);   // exact reference expression z + (z_q - z)
  o.y = zv.y + (cv.y - zv.y);
  o.z = zv.z + (cv.z - zv.z);
  o.w = zv.w + (cv.w - zv.w);
  *(float4*)&out[(size_t)token * DIMC + tid * 4] = o;
  const float ex = cv.x - zv.x, ey = cv.y - zv.y, ez = cv.z - zv.z, ew = cv.w - zv.w;
  float lsum = ex * ex; lsum += ey * ey; lsum += ez * ez; lsum += ew * ew;
#pragma unroll
  for (int off = 32; off; off >>= 1) lsum += __shfl_down(lsum, off);
  if ((tid & 63) == 0) unsafeAtomicAdd(loss_acc, (double)lsum);
}

// ---- per-code gather-sum, fused EMA update + codebook divide + loss write ----
__global__ __launch_bounds__(128)
void persum_kernel(const float* __restrict__ z, const float* __restrict__ ema_sum,
                   const float* __restrict__ ema_cnt,
                   const int* __restrict__ counts, const int* __restrict__ ends,
                   const int* __restrict__ list,
                   float* __restrict__ nes, float* __restrict__ ncb,
                   const double* __restrict__ loss_acc, float* __restrict__ loss_out) {
  const int k = blockIdx.x;       // one code per block
  const int tid = threadIdx.x;    // 128 threads, 4 dims each
  if (k == 0 && tid == 0) {
    const float l = (float)(*loss_acc / 16777216.0);
    loss_out[0] = l;   // loss_commit
    loss_out[1] = l;   // loss_embed (identical forward value)
  }
  const int cnt = counts[k];
  const int start = ends[k] - cnt;      // ends = post-scatter offsets
  float4 s; s.x = s.y = s.z = s.w = 0.f;
  for (int i = 0; i < cnt; ++i) {
    const int tok = list[start + i];
    const float4 zv = *(const float4*)&z[(size_t)tok * DIMC + tid * 4];
    s.x += zv.x; s.y += zv.y; s.z += zv.z; s.w += zv.w;
  }
  const float ncnt = ema_cnt[k] * 0.99f + (float)cnt * 0.01f;
  const float denom = fmaxf(ncnt, 1.0f);
  const size_t base = (size_t)k * DIMC + tid * 4;
  const float4 e = *(const float4*)&ema_sum[base];    // input buffer: 16B aligned
  float2 n0, n1;
  n0.x = e.x * 0.99f + s.x * 0.01f; n0.y = e.y * 0.99f + s.y * 0.01f;
  n1.x = e.z * 0.99f + s.z * 0.01f; n1.y = e.w * 0.99f + s.w * 0.01f;
  *(float2*)&nes[base] = n0;                          // out slots: 8B aligned only
  *(float2*)&nes[base + 2] = n1;
  float2 q0, q1;
  q0.x = n0.x / denom; q0.y = n0.y / denom;
  q1.x = n1.x / denom; q1.y = n1.y / denom;
  *(float2*)&ncb[base] = q0;
  *(float2*)&ncb[base + 2] = q1;
}

extern "C" void kernel_launch(void* const* d_in, const int* in_sizes, int n_in,
                              void* d_out, int out_size, void* d_ws, size_t ws_size,
                              hipStream_t stream) {
  const float* z       = (const float*)d_in[0];
  const float* cb      = (const float*)d_in[1];
  const float* ema_cnt = (const float*)d_in[2];
  const float* ema_sum = (const float*)d_in[3];
  float* out = (float*)d_out;
  char* ws = (char*)d_ws;

  // bf16 operand scratch lives in not-yet-written output regions:
  //   zh/zl -> z_q slot (64MB exactly); ch -> NCB slot (+2 floats for 16B align);
  //   cl -> NES slot (+2). All overwritten by real outputs later in the stream.
  u16* zh = (u16*)out;
  u16* zl = (u16*)(out + 8388608);
  u16* ch = (u16*)(out + OFF_NCB + 2);
  u16* cl = (u16*)(out + OFF_NES + 2);
  unsigned long long* keys = (unsigned long long*)ws;   // [32768] packed (dist,idx)
  float* z2      = (float*)(ws + 262144);
  float* c2      = (float*)(ws + 393216);
  double* loss   = (double*)(ws + 425984);
  int* counts    = (int*)(ws + 426240);    // [8192]
  int* offsets   = (int*)(ws + 459008);    // [8192]
  int* list      = (int*)(ws + 491776);    // [32768]  (ends at 622848 < ws cap)

  conv_norms<<<10240, 256, 0, stream>>>(z, cb, zh, zl, ch, cl, z2, c2);
  init_kernel<<<128, 256, 0, stream>>>(keys, counts, loss);
  argmin_kernel<<<dim3(256, 64), 256, 0, stream>>>(zh, zl, ch, cl, z2, c2, keys);
  hist_kernel<<<128, 256, 0, stream>>>(keys, counts, out + OFF_IDX);
  scan_kernel<<<1, 1024, 0, stream>>>(counts, offsets, ema_cnt,
                                      out + OFF_USAGE, out + OFF_NEC);
  scatter_kernel<<<128, 256, 0, stream>>>(keys, offsets, list);
  zq_loss_kernel<<<NTOK, 128, 0, stream>>>(z, cb, keys, out, loss);
  persum_kernel<<<KCB, 128, 0, stream>>>(z, ema_sum, ema_cnt, counts, offsets, list,
                                         out + OFF_NES, out + OFF_NCB,
                                         loss, out + OFF_LC);
}